// Round 9
// baseline (234.361 us; speedup 1.0000x reference)
//
#include <hip/hip_runtime.h>
#include <stdint.h>
#include <math.h>

#define N_NODES   100000
#define N_EDGES   1600000
#define NFEAT     100
#define HIDDEN    32
#define OUTC      2

#define BUCK_BITS 7
#define BUCK_SZ   128
#define NBUCK     782                       // ceil(100000/128)

#define PART_NB   256
#define PART_CHUNK ((N_EDGES + PART_NB - 1) / PART_NB)   // 6250

typedef float fx4 __attribute__((ext_vector_type(4)));   // nontemporal-compatible

// ---------------------------------------------------------------------------
// JAX threefry2x32, key=(0,42), partitionable: bits(f) = o0^o1
// ---------------------------------------------------------------------------
__device__ __forceinline__ uint32_t rotl32(uint32_t x, int r) {
    return (x << r) | (x >> (32 - r));
}

__device__ __forceinline__ uint32_t threefry_bits(uint32_t f) {
    const uint32_t ks0 = 0u;
    const uint32_t ks1 = 42u;
    const uint32_t ks2 = 0x1BD11BDAu ^ 0u ^ 42u;
    uint32_t x0 = 0u + ks0;
    uint32_t x1 = f  + ks1;
#define TF_ROUND(r) { x0 += x1; x1 = rotl32(x1, (r)); x1 ^= x0; }
    TF_ROUND(13) TF_ROUND(15) TF_ROUND(26) TF_ROUND(6)
    x0 += ks1; x1 += ks2 + 1u;
    TF_ROUND(17) TF_ROUND(29) TF_ROUND(16) TF_ROUND(24)
    x0 += ks2; x1 += ks0 + 2u;
    TF_ROUND(13) TF_ROUND(15) TF_ROUND(26) TF_ROUND(6)
    x0 += ks0; x1 += ks1 + 3u;
    TF_ROUND(17) TF_ROUND(29) TF_ROUND(16) TF_ROUND(24)
    x0 += ks1; x1 += ks2 + 4u;
    TF_ROUND(13) TF_ROUND(15) TF_ROUND(26) TF_ROUND(6)
    x0 += ks2; x1 += ks0 + 5u;
#undef TF_ROUND
    return x0 ^ x1;
}

__device__ __forceinline__ bool dropout_keep(uint32_t f) {
    uint32_t bits = threefry_bits(f);
    float u = __uint_as_float((bits >> 9) | 0x3f800000u) - 1.0f;
    return u < 0.8f;
}

// float -> bf16 (RNE) and back
__device__ __forceinline__ uint16_t f2bf(float f) {
    uint32_t b = __float_as_uint(f);
    uint32_t lsb = (b >> 16) & 1u;
    b += 0x7fffu + lsb;
    return (uint16_t)(b >> 16);
}
__device__ __forceinline__ float bf2f(uint16_t u) {
    return __uint_as_float((uint32_t)u << 16);
}

// ---------------------------------------------------------------------------
// 1. Bucket histogram via per-block LDS histograms
// ---------------------------------------------------------------------------
__global__ __launch_bounds__(256) void k_bhist(const int* __restrict__ dst,
                                               int* __restrict__ bcnt) {
    __shared__ int h[NBUCK];
    for (int i = threadIdx.x; i < NBUCK; i += 256) h[i] = 0;
    __syncthreads();
    const int stride = gridDim.x * 256;
    for (int e = blockIdx.x * 256 + threadIdx.x; e < N_EDGES; e += stride)
        atomicAdd(&h[dst[e] >> BUCK_BITS], 1);
    __syncthreads();
    for (int i = threadIdx.x; i < NBUCK; i += 256) {
        int v = h[i];
        if (v) atomicAdd(&bcnt[i], v);
    }
}

// ---------------------------------------------------------------------------
// 2. Scan of 782 bucket counts (single block); seed global cursors
// ---------------------------------------------------------------------------
__global__ __launch_bounds__(1024) void k_bscan(const int* __restrict__ bcnt,
                                                int* __restrict__ boff,
                                                int* __restrict__ bcur) {
    __shared__ int lds[1024];
    const int t = threadIdx.x;
    int v = (t < NBUCK) ? bcnt[t] : 0;
    lds[t] = v;
    __syncthreads();
#pragma unroll
    for (int off = 1; off < 1024; off <<= 1) {
        int u = (t >= off) ? lds[t - off] : 0;
        __syncthreads();
        lds[t] += u;
        __syncthreads();
    }
    if (t < NBUCK) {
        int ex = lds[t] - v;
        boff[t] = ex;
        bcur[t] = ex;
    }
    if (t == 0) boff[NBUCK] = N_EDGES;
}

// ---------------------------------------------------------------------------
// 3. Partition with block-aggregated reservation
// ---------------------------------------------------------------------------
__global__ __launch_bounds__(1024) void k_part(const int* __restrict__ src,
                                               const int* __restrict__ dst,
                                               int* __restrict__ bcur,
                                               uint32_t* __restrict__ part) {
    __shared__ int hist[NBUCK];
    __shared__ int cur[NBUCK];
    const int t = threadIdx.x;
    const int base = blockIdx.x * PART_CHUNK;
    const int lim = min(base + PART_CHUNK, N_EDGES);
    if (t < NBUCK) hist[t] = 0;
    __syncthreads();
    for (int e = base + t; e < lim; e += 1024)
        atomicAdd(&hist[dst[e] >> BUCK_BITS], 1);
    __syncthreads();
    if (t < NBUCK) {
        int c = hist[t];
        cur[t] = c ? atomicAdd(&bcur[t], c) : 0;
    }
    __syncthreads();
    for (int e = base + t; e < lim; e += 1024) {
        int d = dst[e];
        int b = d >> BUCK_BITS;
        int pos = atomicAdd(&cur[b], 1);
        part[pos] = ((uint32_t)(d & (BUCK_SZ - 1)) << 17) | (uint32_t)src[e];
    }
}

// ---------------------------------------------------------------------------
// 4. Per-bucket counting sort -> true CSR (csr_src), rowptr, dinv
// ---------------------------------------------------------------------------
__global__ __launch_bounds__(256) void k_sort(const uint32_t* __restrict__ part,
                                              const int* __restrict__ boff,
                                              int* __restrict__ csr_src,
                                              int* __restrict__ rowptr,
                                              float* __restrict__ dinv) {
    __shared__ int cnt[BUCK_SZ];
    __shared__ int pref[BUCK_SZ];
    __shared__ int cur[BUCK_SZ];
    const int b = blockIdx.x;
    const int t = threadIdx.x;
    const int nbase = b * BUCK_SZ;
    const int bb = boff[b], be = boff[b + 1];
    if (t < BUCK_SZ) cnt[t] = 0;
    __syncthreads();
    for (int j = bb + t; j < be; j += 256)
        atomicAdd(&cnt[(part[j] >> 17) & (BUCK_SZ - 1)], 1);
    __syncthreads();
    if (t < BUCK_SZ) pref[t] = cnt[t];
    __syncthreads();
#pragma unroll
    for (int off = 1; off < BUCK_SZ; off <<= 1) {
        int v = (t >= off && t < BUCK_SZ) ? pref[t - off] : 0;
        __syncthreads();
        if (t < BUCK_SZ) pref[t] += v;
        __syncthreads();
    }
    if (t < BUCK_SZ) {
        int ex = pref[t] - cnt[t];
        cur[t] = ex;
        int node = nbase + t;
        if (node < N_NODES) {
            rowptr[node] = bb + ex;
            dinv[node] = rsqrtf((float)(cnt[t] + 1));
        }
    }
    if (b == NBUCK - 1 && t == 0) rowptr[N_NODES] = N_EDGES;
    __syncthreads();
    for (int j = bb + t; j < be; j += 256) {
        uint32_t v = part[j];
        int dl = (v >> 17) & (BUCK_SZ - 1);
        int pos = bb + atomicAdd(&cur[dl], 1);
        csr_src[pos] = (int)(v & 0x1FFFF);
    }
}

// ---------------------------------------------------------------------------
// 5. h0b = bf16((x @ W1) * dinv[row]) — halves layer-1 gather traffic.
//    x read via nontemporal (read-once, keep L2 for gathers).
// ---------------------------------------------------------------------------
__global__ __launch_bounds__(256) void k_gemm1(const float* __restrict__ x,
                                               const float* __restrict__ W1,
                                               const float* __restrict__ dinv,
                                               uint16_t* __restrict__ h0b) {
    __shared__ __align__(16) float w1s[NFEAT * HIDDEN];
    __shared__ __align__(16) float xs[8 * NFEAT];
    const int tid = threadIdx.x;
    for (int i = tid; i < NFEAT * HIDDEN / 4; i += 256)
        ((fx4*)w1s)[i] = ((const fx4*)W1)[i];
    const int row0 = blockIdx.x * 8;
    const fx4* xb = (const fx4*)(x + (size_t)row0 * NFEAT);
    if (tid < 200) ((fx4*)xs)[tid] = __builtin_nontemporal_load(&xb[tid]);
    __syncthreads();
    const int r = tid >> 5, c = tid & 31;
    float acc = 0.0f;
#pragma unroll 4
    for (int k = 0; k < NFEAT; ++k)
        acc = fmaf(xs[r * NFEAT + k], w1s[k * HIDDEN + c], acc);
    int row = row0 + r;
    h0b[(size_t)row * HIDDEN + c] = f2bf(acc * dinv[row]);
}

// ---------------------------------------------------------------------------
// 6. Layer 1: register-pull CSR aggregation over bf16 rows, 32 lanes/node,
//    4x unrolled gathers; + b1 + ReLU + dropout + @W2 reduce.
// ---------------------------------------------------------------------------
__global__ __launch_bounds__(256) void k_l1(const int* __restrict__ rowptr,
                                            const int* __restrict__ csr_src,
                                            const float* __restrict__ dinv,
                                            const uint16_t* __restrict__ h0b,
                                            const float* __restrict__ b1,
                                            const float* __restrict__ W2,
                                            float* __restrict__ h2s) {
    int t = blockIdx.x * 256 + threadIdx.x;
    int n = t >> 5;
    int c = t & 31;
    if (n >= N_NODES) return;
    float a0 = bf2f(h0b[(size_t)n * HIDDEN + c]);   // self loop (pre-scaled)
    float a1 = 0.0f, a2 = 0.0f, a3 = 0.0f;
    int j = rowptr[n];
    const int end = rowptr[n + 1];
    for (; j + 3 < end; j += 4) {
        int s0 = __builtin_nontemporal_load(&csr_src[j]);
        int s1 = __builtin_nontemporal_load(&csr_src[j + 1]);
        int s2 = __builtin_nontemporal_load(&csr_src[j + 2]);
        int s3 = __builtin_nontemporal_load(&csr_src[j + 3]);
        uint16_t u0 = h0b[(size_t)s0 * HIDDEN + c];
        uint16_t u1 = h0b[(size_t)s1 * HIDDEN + c];
        uint16_t u2 = h0b[(size_t)s2 * HIDDEN + c];
        uint16_t u3 = h0b[(size_t)s3 * HIDDEN + c];
        a0 += bf2f(u0);
        a1 += bf2f(u1);
        a2 += bf2f(u2);
        a3 += bf2f(u3);
    }
    for (; j < end; ++j)
        a0 += bf2f(h0b[(size_t)__builtin_nontemporal_load(&csr_src[j]) * HIDDEN + c]);
    float acc = (a0 + a1) + (a2 + a3);
    float din = dinv[n];
    float v = fmaxf(fmaf(acc, din, b1[c]), 0.0f);
    v = dropout_keep((uint32_t)(n * HIDDEN + c)) ? v * 1.25f : 0.0f;
    float p0 = v * W2[c * 2 + 0];
    float p1 = v * W2[c * 2 + 1];
#pragma unroll
    for (int m = 16; m >= 1; m >>= 1) {
        p0 += __shfl_xor(p0, m);
        p1 += __shfl_xor(p1, m);
    }
    if (c == 0) {
        float2* o = (float2*)(h2s + (size_t)n * 2);
        *o = make_float2(p0 * din, p1 * din);
    }
}

// ---------------------------------------------------------------------------
// 7. Layer 2: register-pull CSR, 8 lanes/node, 2x unrolled float2 gathers,
//    + b2 + log_softmax.
// ---------------------------------------------------------------------------
__global__ __launch_bounds__(256) void k_l2(const int* __restrict__ rowptr,
                                            const int* __restrict__ csr_src,
                                            const float* __restrict__ dinv,
                                            const float* __restrict__ h2s,
                                            const float* __restrict__ b2,
                                            float* __restrict__ out) {
    int t = blockIdx.x * 256 + threadIdx.x;
    int n = t >> 3;
    int l = t & 7;
    if (n >= N_NODES) return;
    float acc0 = 0.0f, acc1 = 0.0f;
    float bcc0 = 0.0f, bcc1 = 0.0f;
    if (l == 0) {
        float2 hn = ((const float2*)h2s)[n];
        acc0 = hn.x; acc1 = hn.y;
    }
    int j = rowptr[n] + l;
    const int end = rowptr[n + 1];
    for (; j + 8 < end; j += 16) {
        int s0 = __builtin_nontemporal_load(&csr_src[j]);
        int s1 = __builtin_nontemporal_load(&csr_src[j + 8]);
        float2 h0v = ((const float2*)h2s)[s0];
        float2 h1v = ((const float2*)h2s)[s1];
        acc0 += h0v.x; acc1 += h0v.y;
        bcc0 += h1v.x; bcc1 += h1v.y;
    }
    if (j < end) {
        float2 hv = ((const float2*)h2s)[__builtin_nontemporal_load(&csr_src[j])];
        acc0 += hv.x; acc1 += hv.y;
    }
    acc0 += bcc0; acc1 += bcc1;
#pragma unroll
    for (int m = 4; m >= 1; m >>= 1) {
        acc0 += __shfl_xor(acc0, m);
        acc1 += __shfl_xor(acc1, m);
    }
    if (l == 0) {
        float din = dinv[n];
        float l0 = fmaf(acc0, din, b2[0]);
        float l1 = fmaf(acc1, din, b2[1]);
        float m = fmaxf(l0, l1);
        float lse = m + logf(expf(l0 - m) + expf(l1 - m));
        float2* o = (float2*)(out + (size_t)n * 2);
        *o = make_float2(l0 - lse, l1 - lse);
    }
}

// ---------------------------------------------------------------------------
// Launch
// ---------------------------------------------------------------------------
static inline size_t align_up(size_t x) { return (x + 255) & ~(size_t)255; }

extern "C" void kernel_launch(void* const* d_in, const int* in_sizes, int n_in,
                              void* d_out, int out_size, void* d_ws, size_t ws_size,
                              hipStream_t stream) {
    (void)n_in; (void)in_sizes; (void)out_size; (void)ws_size;

    const float* x  = (const float*)d_in[0];
    const int*   ei = (const int*)d_in[1];
    const float* W1 = (const float*)d_in[2];
    const float* b1 = (const float*)d_in[3];
    const float* W2 = (const float*)d_in[4];
    const float* b2 = (const float*)d_in[5];
    float* out = (float*)d_out;

    const int* src = ei;
    const int* dst = ei + N_EDGES;

    char* w = (char*)d_ws;
    size_t off = 0;
    int*      bcnt   = (int*)(w + off);      off += align_up((size_t)NBUCK * 4);
    int*      boff   = (int*)(w + off);      off += align_up((size_t)(NBUCK + 1) * 4);
    int*      bcur   = (int*)(w + off);      off += align_up((size_t)NBUCK * 4);
    int*      rowptr = (int*)(w + off);      off += align_up((size_t)(N_NODES + 1) * 4);
    float*    dinv   = (float*)(w + off);    off += align_up((size_t)N_NODES * 4);
    uint32_t* part   = (uint32_t*)(w + off); off += align_up((size_t)N_EDGES * 4);
    int*      csr    = (int*)(w + off);      off += align_up((size_t)N_EDGES * 4);
    uint16_t* h0b    = (uint16_t*)(w + off); off += align_up((size_t)N_NODES * HIDDEN * 2);
    float*    h2s    = (float*)(w + off);    off += align_up((size_t)N_NODES * OUTC * 4);

    (void)hipMemsetAsync(bcnt, 0, (size_t)NBUCK * 4, stream);

    const int B = 256;
    k_bhist<<<256, B, 0, stream>>>(dst, bcnt);
    k_bscan<<<1, 1024, 0, stream>>>(bcnt, boff, bcur);
    k_part <<<PART_NB, 1024, 0, stream>>>(src, dst, bcur, part);
    k_sort <<<NBUCK, B, 0, stream>>>(part, boff, csr, rowptr, dinv);
    k_gemm1<<<N_NODES / 8, B, 0, stream>>>(x, W1, dinv, h0b);
    k_l1   <<<(N_NODES * HIDDEN + B - 1) / B, B, 0, stream>>>(rowptr, csr, dinv, h0b, b1, W2, h2s);
    k_l2   <<<(N_NODES * 8 + B - 1) / B, B, 0, stream>>>(rowptr, csr, dinv, h2s, b2, out);
}

// Round 10
// 199.224 us; speedup vs baseline: 1.1764x; 1.1764x over previous
//
#include <hip/hip_runtime.h>
#include <stdint.h>
#include <math.h>

#define N_NODES   100000
#define N_EDGES   1600000
#define NFEAT     100
#define HIDDEN    32
#define OUTC      2

#define BUCK_BITS 7
#define BUCK_SZ   128
#define NBUCK     782                       // ceil(100000/128)

#define PART_NB   256
#define PART_CHUNK ((N_EDGES + PART_NB - 1) / PART_NB)   // 6250

typedef float fx4 __attribute__((ext_vector_type(4)));

// ---------------------------------------------------------------------------
// JAX threefry2x32, key=(0,42), partitionable: bits(f) = o0^o1
// ---------------------------------------------------------------------------
__device__ __forceinline__ uint32_t rotl32(uint32_t x, int r) {
    return (x << r) | (x >> (32 - r));
}

__device__ __forceinline__ uint32_t threefry_bits(uint32_t f) {
    const uint32_t ks0 = 0u;
    const uint32_t ks1 = 42u;
    const uint32_t ks2 = 0x1BD11BDAu ^ 0u ^ 42u;
    uint32_t x0 = 0u + ks0;
    uint32_t x1 = f  + ks1;
#define TF_ROUND(r) { x0 += x1; x1 = rotl32(x1, (r)); x1 ^= x0; }
    TF_ROUND(13) TF_ROUND(15) TF_ROUND(26) TF_ROUND(6)
    x0 += ks1; x1 += ks2 + 1u;
    TF_ROUND(17) TF_ROUND(29) TF_ROUND(16) TF_ROUND(24)
    x0 += ks2; x1 += ks0 + 2u;
    TF_ROUND(13) TF_ROUND(15) TF_ROUND(26) TF_ROUND(6)
    x0 += ks0; x1 += ks1 + 3u;
    TF_ROUND(17) TF_ROUND(29) TF_ROUND(16) TF_ROUND(24)
    x0 += ks1; x1 += ks2 + 4u;
    TF_ROUND(13) TF_ROUND(15) TF_ROUND(26) TF_ROUND(6)
    x0 += ks2; x1 += ks0 + 5u;
#undef TF_ROUND
    return x0 ^ x1;
}

__device__ __forceinline__ bool dropout_keep(uint32_t f) {
    uint32_t bits = threefry_bits(f);
    float u = __uint_as_float((bits >> 9) | 0x3f800000u) - 1.0f;
    return u < 0.8f;
}

// float -> bf16 (RNE); packed bf16 pair unpack
__device__ __forceinline__ uint16_t f2bf(float f) {
    uint32_t b = __float_as_uint(f);
    uint32_t lsb = (b >> 16) & 1u;
    b += 0x7fffu + lsb;
    return (uint16_t)(b >> 16);
}
__device__ __forceinline__ float bflo(uint32_t u) {   // element 2l   (low ushort)
    return __uint_as_float(u << 16);
}
__device__ __forceinline__ float bfhi(uint32_t u) {   // element 2l+1 (high ushort)
    return __uint_as_float(u & 0xffff0000u);
}

// ---------------------------------------------------------------------------
// 1. Bucket histogram, 4-way wave-split LDS sub-histograms
// ---------------------------------------------------------------------------
__global__ __launch_bounds__(256) void k_bhist(const int* __restrict__ dst,
                                               int* __restrict__ bcnt) {
    __shared__ int h4[4][NBUCK];
    const int t = threadIdx.x;
    const int w = t >> 6;   // wave id 0..3
    for (int i = t; i < 4 * NBUCK; i += 256) ((int*)h4)[i] = 0;
    __syncthreads();
    const int stride = gridDim.x * 256;
    for (int e = blockIdx.x * 256 + t; e < N_EDGES; e += stride)
        atomicAdd(&h4[w][dst[e] >> BUCK_BITS], 1);
    __syncthreads();
    for (int i = t; i < NBUCK; i += 256) {
        int v = h4[0][i] + h4[1][i] + h4[2][i] + h4[3][i];
        if (v) atomicAdd(&bcnt[i], v);
    }
}

// ---------------------------------------------------------------------------
// 2. Scan of 782 bucket counts (single block); seed global cursors
// ---------------------------------------------------------------------------
__global__ __launch_bounds__(1024) void k_bscan(const int* __restrict__ bcnt,
                                                int* __restrict__ boff,
                                                int* __restrict__ bcur) {
    __shared__ int lds[1024];
    const int t = threadIdx.x;
    int v = (t < NBUCK) ? bcnt[t] : 0;
    lds[t] = v;
    __syncthreads();
#pragma unroll
    for (int off = 1; off < 1024; off <<= 1) {
        int u = (t >= off) ? lds[t - off] : 0;
        __syncthreads();
        lds[t] += u;
        __syncthreads();
    }
    if (t < NBUCK) {
        int ex = lds[t] - v;
        boff[t] = ex;
        bcur[t] = ex;
    }
    if (t == 0) boff[NBUCK] = N_EDGES;
}

// ---------------------------------------------------------------------------
// 3. Partition, block-aggregated reservation + 4-way wave-split cursors
// ---------------------------------------------------------------------------
__global__ __launch_bounds__(1024) void k_part(const int* __restrict__ src,
                                               const int* __restrict__ dst,
                                               int* __restrict__ bcur,
                                               uint32_t* __restrict__ part) {
    __shared__ int h4[4][NBUCK];
    __shared__ int c4[4][NBUCK];
    const int t = threadIdx.x;
    const int w = (t >> 6) & 3;   // wave slot (4 waves share a slot)
    const int base = blockIdx.x * PART_CHUNK;
    const int lim = min(base + PART_CHUNK, N_EDGES);
    for (int i = t; i < 4 * NBUCK; i += 1024) ((int*)h4)[i] = 0;
    __syncthreads();
    for (int e = base + t; e < lim; e += 1024)
        atomicAdd(&h4[w][dst[e] >> BUCK_BITS], 1);
    __syncthreads();
    if (t < NBUCK) {
        int c0 = h4[0][t], c1 = h4[1][t], c2 = h4[2][t], c3 = h4[3][t];
        int tot = c0 + c1 + c2 + c3;
        int g = tot ? atomicAdd(&bcur[t], tot) : 0;
        c4[0][t] = g;
        c4[1][t] = g + c0;
        c4[2][t] = g + c0 + c1;
        c4[3][t] = g + c0 + c1 + c2;
    }
    __syncthreads();
    for (int e = base + t; e < lim; e += 1024) {
        int d = dst[e];
        int b = d >> BUCK_BITS;
        int pos = atomicAdd(&c4[w][b], 1);
        part[pos] = ((uint32_t)(d & (BUCK_SZ - 1)) << 17) | (uint32_t)src[e];
    }
}

// ---------------------------------------------------------------------------
// 4. Per-bucket counting sort -> CSR; 4-way wave-split histogram + cursors
// ---------------------------------------------------------------------------
__global__ __launch_bounds__(256) void k_sort(const uint32_t* __restrict__ part,
                                              const int* __restrict__ boff,
                                              int* __restrict__ csr_src,
                                              int* __restrict__ rowptr,
                                              float* __restrict__ dinv) {
    __shared__ int cnt4[4][BUCK_SZ];
    __shared__ int pref[BUCK_SZ];
    __shared__ int cur4[4][BUCK_SZ];
    const int b = blockIdx.x;
    const int t = threadIdx.x;
    const int w = t >> 6;
    const int nbase = b * BUCK_SZ;
    const int bb = boff[b], be = boff[b + 1];
    for (int i = t; i < 4 * BUCK_SZ; i += 256) ((int*)cnt4)[i] = 0;
    __syncthreads();
    for (int j = bb + t; j < be; j += 256)
        atomicAdd(&cnt4[w][(part[j] >> 17) & (BUCK_SZ - 1)], 1);
    __syncthreads();
    int c0 = 0, c1 = 0, c2 = 0, tot = 0;
    if (t < BUCK_SZ) {
        c0 = cnt4[0][t]; c1 = cnt4[1][t]; c2 = cnt4[2][t];
        tot = c0 + c1 + c2 + cnt4[3][t];
        pref[t] = tot;
    }
    __syncthreads();
#pragma unroll
    for (int off = 1; off < BUCK_SZ; off <<= 1) {
        int v = (t >= off && t < BUCK_SZ) ? pref[t - off] : 0;
        __syncthreads();
        if (t < BUCK_SZ) pref[t] += v;
        __syncthreads();
    }
    if (t < BUCK_SZ) {
        int ex = pref[t] - tot;
        cur4[0][t] = ex;
        cur4[1][t] = ex + c0;
        cur4[2][t] = ex + c0 + c1;
        cur4[3][t] = ex + c0 + c1 + c2;
        int node = nbase + t;
        if (node < N_NODES) {
            rowptr[node] = bb + ex;
            dinv[node] = rsqrtf((float)(tot + 1));
        }
    }
    if (b == NBUCK - 1 && t == 0) rowptr[N_NODES] = N_EDGES;
    __syncthreads();
    for (int j = bb + t; j < be; j += 256) {
        uint32_t v = part[j];
        int dl = (v >> 17) & (BUCK_SZ - 1);
        int pos = bb + atomicAdd(&cur4[w][dl], 1);
        csr_src[pos] = (int)(v & 0x1FFFF);
    }
}

// ---------------------------------------------------------------------------
// 5. h0b = bf16((x @ W1) * dinv[row]); 32 rows/block, 4 outputs/thread
// ---------------------------------------------------------------------------
__global__ __launch_bounds__(256) void k_gemm1(const float* __restrict__ x,
                                               const float* __restrict__ W1,
                                               const float* __restrict__ dinv,
                                               uint16_t* __restrict__ h0b) {
    __shared__ __align__(16) float w1s[NFEAT * HIDDEN];   // 12.8 KB
    __shared__ __align__(16) float xs[32 * NFEAT];        // 12.8 KB
    const int tid = threadIdx.x;
    for (int i = tid; i < NFEAT * HIDDEN / 4; i += 256)
        ((fx4*)w1s)[i] = ((const fx4*)W1)[i];
    const int row0 = blockIdx.x * 32;
    const fx4* xb = (const fx4*)(x + (size_t)row0 * NFEAT);   // 800 fx4
    for (int i = tid; i < 800; i += 256)
        ((fx4*)xs)[i] = __builtin_nontemporal_load(&xb[i]);
    __syncthreads();
    const int c = tid & 31, r0 = tid >> 5;   // rows r0, r0+8, r0+16, r0+24
    float a0 = 0.f, a1 = 0.f, a2 = 0.f, a3 = 0.f;
#pragma unroll 4
    for (int k = 0; k < NFEAT; ++k) {
        float wv = w1s[k * HIDDEN + c];
        a0 = fmaf(xs[(r0)      * NFEAT + k], wv, a0);
        a1 = fmaf(xs[(r0 + 8)  * NFEAT + k], wv, a1);
        a2 = fmaf(xs[(r0 + 16) * NFEAT + k], wv, a2);
        a3 = fmaf(xs[(r0 + 24) * NFEAT + k], wv, a3);
    }
    const int r = row0 + r0;
    h0b[(size_t)(r)      * HIDDEN + c] = f2bf(a0 * dinv[r]);
    h0b[(size_t)(r + 8)  * HIDDEN + c] = f2bf(a1 * dinv[r + 8]);
    h0b[(size_t)(r + 16) * HIDDEN + c] = f2bf(a2 * dinv[r + 16]);
    h0b[(size_t)(r + 24) * HIDDEN + c] = f2bf(a3 * dinv[r + 24]);
}

// ---------------------------------------------------------------------------
// 6. Layer 1: 16 lanes/node, uint (2xbf16) gathers => 4 edges per wave
//    instruction; software-pipelined csr index prefetch hides csr latency.
// ---------------------------------------------------------------------------
__global__ __launch_bounds__(256) void k_l1(const int* __restrict__ rowptr,
                                            const int* __restrict__ csr_src,
                                            const float* __restrict__ dinv,
                                            const uint32_t* __restrict__ h0u,
                                            const float* __restrict__ b1,
                                            const float* __restrict__ W2,
                                            float* __restrict__ h2s) {
    const int t = blockIdx.x * 256 + threadIdx.x;
    const int n = t >> 4;        // 16 nodes per block (grid exact)
    const int l = t & 15;        // lane in 16-group; columns 2l, 2l+1
    uint32_t self = h0u[(size_t)n * 16 + l];
    float accL = bflo(self), accH = bfhi(self);
    const int beg = rowptr[n], end = rowptr[n + 1];
    const int mainEnd = beg + ((end - beg) & ~3);
    int j = beg;
    int s0, s1, s2, s3;
    if (j < mainEnd) {
        s0 = csr_src[j]; s1 = csr_src[j + 1];
        s2 = csr_src[j + 2]; s3 = csr_src[j + 3];
    }
    for (; j < mainEnd; j += 4) {
        uint32_t u0 = h0u[(size_t)s0 * 16 + l];
        uint32_t u1 = h0u[(size_t)s1 * 16 + l];
        uint32_t u2 = h0u[(size_t)s2 * 16 + l];
        uint32_t u3 = h0u[(size_t)s3 * 16 + l];
        // prefetch next iteration's indices (clamped; issues before the
        // accumulate waits on u0..u3)
        int pj = (j + 8 <= mainEnd) ? j + 4 : beg;
        s0 = csr_src[pj];     s1 = csr_src[pj + 1];
        s2 = csr_src[pj + 2]; s3 = csr_src[pj + 3];
        accL += bflo(u0); accH += bfhi(u0);
        accL += bflo(u1); accH += bfhi(u1);
        accL += bflo(u2); accH += bfhi(u2);
        accL += bflo(u3); accH += bfhi(u3);
    }
    for (; j < end; ++j) {
        uint32_t u = h0u[(size_t)csr_src[j] * 16 + l];
        accL += bflo(u); accH += bfhi(u);
    }
    const int c0 = 2 * l, c1 = 2 * l + 1;
    const float din = dinv[n];
    float v0 = fmaxf(fmaf(accL, din, b1[c0]), 0.0f);
    float v1 = fmaxf(fmaf(accH, din, b1[c1]), 0.0f);
    v0 = dropout_keep((uint32_t)(n * HIDDEN + c0)) ? v0 * 1.25f : 0.0f;
    v1 = dropout_keep((uint32_t)(n * HIDDEN + c1)) ? v1 * 1.25f : 0.0f;
    float p0 = v0 * W2[c0 * 2 + 0] + v1 * W2[c1 * 2 + 0];
    float p1 = v0 * W2[c0 * 2 + 1] + v1 * W2[c1 * 2 + 1];
#pragma unroll
    for (int m = 8; m >= 1; m >>= 1) {
        p0 += __shfl_xor(p0, m);
        p1 += __shfl_xor(p1, m);
    }
    if (l == 0) {
        float2* o = (float2*)(h2s + (size_t)n * 2);
        *o = make_float2(p0 * din, p1 * din);
    }
}

// ---------------------------------------------------------------------------
// 7. Layer 2: register-pull CSR, 8 lanes/node, 2x unrolled float2 gathers,
//    + b2 + log_softmax. csr read nontemporal (last reader).
// ---------------------------------------------------------------------------
__global__ __launch_bounds__(256) void k_l2(const int* __restrict__ rowptr,
                                            const int* __restrict__ csr_src,
                                            const float* __restrict__ dinv,
                                            const float* __restrict__ h2s,
                                            const float* __restrict__ b2,
                                            float* __restrict__ out) {
    int t = blockIdx.x * 256 + threadIdx.x;
    int n = t >> 3;
    int l = t & 7;
    if (n >= N_NODES) return;
    float acc0 = 0.0f, acc1 = 0.0f;
    float bcc0 = 0.0f, bcc1 = 0.0f;
    if (l == 0) {
        float2 hn = ((const float2*)h2s)[n];
        acc0 = hn.x; acc1 = hn.y;
    }
    int j = rowptr[n] + l;
    const int end = rowptr[n + 1];
    for (; j + 8 < end; j += 16) {
        int s0 = __builtin_nontemporal_load(&csr_src[j]);
        int s1 = __builtin_nontemporal_load(&csr_src[j + 8]);
        float2 h0v = ((const float2*)h2s)[s0];
        float2 h1v = ((const float2*)h2s)[s1];
        acc0 += h0v.x; acc1 += h0v.y;
        bcc0 += h1v.x; bcc1 += h1v.y;
    }
    if (j < end) {
        float2 hv = ((const float2*)h2s)[__builtin_nontemporal_load(&csr_src[j])];
        acc0 += hv.x; acc1 += hv.y;
    }
    acc0 += bcc0; acc1 += bcc1;
#pragma unroll
    for (int m = 4; m >= 1; m >>= 1) {
        acc0 += __shfl_xor(acc0, m);
        acc1 += __shfl_xor(acc1, m);
    }
    if (l == 0) {
        float din = dinv[n];
        float l0 = fmaf(acc0, din, b2[0]);
        float l1 = fmaf(acc1, din, b2[1]);
        float m = fmaxf(l0, l1);
        float lse = m + logf(expf(l0 - m) + expf(l1 - m));
        float2* o = (float2*)(out + (size_t)n * 2);
        *o = make_float2(l0 - lse, l1 - lse);
    }
}

// ---------------------------------------------------------------------------
// Launch
// ---------------------------------------------------------------------------
static inline size_t align_up(size_t x) { return (x + 255) & ~(size_t)255; }

extern "C" void kernel_launch(void* const* d_in, const int* in_sizes, int n_in,
                              void* d_out, int out_size, void* d_ws, size_t ws_size,
                              hipStream_t stream) {
    (void)n_in; (void)in_sizes; (void)out_size; (void)ws_size;

    const float* x  = (const float*)d_in[0];
    const int*   ei = (const int*)d_in[1];
    const float* W1 = (const float*)d_in[2];
    const float* b1 = (const float*)d_in[3];
    const float* W2 = (const float*)d_in[4];
    const float* b2 = (const float*)d_in[5];
    float* out = (float*)d_out;

    const int* src = ei;
    const int* dst = ei + N_EDGES;

    char* w = (char*)d_ws;
    size_t off = 0;
    int*      bcnt   = (int*)(w + off);      off += align_up((size_t)NBUCK * 4);
    int*      boff   = (int*)(w + off);      off += align_up((size_t)(NBUCK + 1) * 4);
    int*      bcur   = (int*)(w + off);      off += align_up((size_t)NBUCK * 4);
    int*      rowptr = (int*)(w + off);      off += align_up((size_t)(N_NODES + 1) * 4);
    float*    dinv   = (float*)(w + off);    off += align_up((size_t)N_NODES * 4);
    uint32_t* part   = (uint32_t*)(w + off); off += align_up((size_t)N_EDGES * 4);
    int*      csr    = (int*)(w + off);      off += align_up((size_t)N_EDGES * 4);
    uint16_t* h0b    = (uint16_t*)(w + off); off += align_up((size_t)N_NODES * HIDDEN * 2);
    float*    h2s    = (float*)(w + off);    off += align_up((size_t)N_NODES * OUTC * 4);

    (void)hipMemsetAsync(bcnt, 0, (size_t)NBUCK * 4, stream);

    const int B = 256;
    k_bhist<<<256, B, 0, stream>>>(dst, bcnt);
    k_bscan<<<1, 1024, 0, stream>>>(bcnt, boff, bcur);
    k_part <<<PART_NB, 1024, 0, stream>>>(src, dst, bcur, part);
    k_sort <<<NBUCK, B, 0, stream>>>(part, boff, csr, rowptr, dinv);
    k_gemm1<<<N_NODES / 32, B, 0, stream>>>(x, W1, dinv, h0b);
    k_l1   <<<N_NODES / 16, B, 0, stream>>>(rowptr, csr, dinv, (const uint32_t*)h0b, b1, W2, h2s);
    k_l2   <<<(N_NODES * 8 + B - 1) / B, B, 0, stream>>>(rowptr, csr, dinv, h2s, b2, out);
}

// Round 11
// 178.728 us; speedup vs baseline: 1.3113x; 1.1147x over previous
//
#include <hip/hip_runtime.h>
#include <stdint.h>
#include <math.h>

#define N_NODES   100000
#define N_EDGES   1600000
#define NFEAT     100
#define HIDDEN    32
#define OUTC      2

#define BUCK_BITS 7
#define BUCK_SZ   128
#define NBUCK     782                       // ceil(100000/128)
#define PADB      4096                      // padded window per bucket (>40 sigma)

#define PART_NB   256
#define PART_CHUNK ((N_EDGES + PART_NB - 1) / PART_NB)   // 6250

typedef float fx4 __attribute__((ext_vector_type(4)));

// ---------------------------------------------------------------------------
// JAX threefry2x32, key=(0,42), partitionable: bits(f) = o0^o1
// ---------------------------------------------------------------------------
__device__ __forceinline__ uint32_t rotl32(uint32_t x, int r) {
    return (x << r) | (x >> (32 - r));
}

__device__ __forceinline__ uint32_t threefry_bits(uint32_t f) {
    const uint32_t ks0 = 0u;
    const uint32_t ks1 = 42u;
    const uint32_t ks2 = 0x1BD11BDAu ^ 0u ^ 42u;
    uint32_t x0 = 0u + ks0;
    uint32_t x1 = f  + ks1;
#define TF_ROUND(r) { x0 += x1; x1 = rotl32(x1, (r)); x1 ^= x0; }
    TF_ROUND(13) TF_ROUND(15) TF_ROUND(26) TF_ROUND(6)
    x0 += ks1; x1 += ks2 + 1u;
    TF_ROUND(17) TF_ROUND(29) TF_ROUND(16) TF_ROUND(24)
    x0 += ks2; x1 += ks0 + 2u;
    TF_ROUND(13) TF_ROUND(15) TF_ROUND(26) TF_ROUND(6)
    x0 += ks0; x1 += ks1 + 3u;
    TF_ROUND(17) TF_ROUND(29) TF_ROUND(16) TF_ROUND(24)
    x0 += ks1; x1 += ks2 + 4u;
    TF_ROUND(13) TF_ROUND(15) TF_ROUND(26) TF_ROUND(6)
    x0 += ks2; x1 += ks0 + 5u;
#undef TF_ROUND
    return x0 ^ x1;
}

__device__ __forceinline__ bool dropout_keep(uint32_t f) {
    uint32_t bits = threefry_bits(f);
    float u = __uint_as_float((bits >> 9) | 0x3f800000u) - 1.0f;
    return u < 0.8f;
}

// float -> bf16 (RNE); packed bf16 pair unpack
__device__ __forceinline__ uint16_t f2bf(float f) {
    uint32_t b = __float_as_uint(f);
    uint32_t lsb = (b >> 16) & 1u;
    b += 0x7fffu + lsb;
    return (uint16_t)(b >> 16);
}
__device__ __forceinline__ float bflo(uint32_t u) {   // low ushort = even col
    return __uint_as_float(u << 16);
}
__device__ __forceinline__ float bfhi(uint32_t u) {   // high ushort = odd col
    return __uint_as_float(u & 0xffff0000u);
}

// ---------------------------------------------------------------------------
// 0. Seed bucket cursors to fixed padded bases (replaces hist+scan+memset)
// ---------------------------------------------------------------------------
__global__ __launch_bounds__(256) void k_init(int* __restrict__ bcur) {
    int i = blockIdx.x * 256 + threadIdx.x;
    if (i < NBUCK) bcur[i] = i * PADB;
}

// ---------------------------------------------------------------------------
// 1. Partition into padded bucket windows; block-aggregated reservation +
//    4-way wave-split LDS cursors.
// ---------------------------------------------------------------------------
__global__ __launch_bounds__(1024) void k_part(const int* __restrict__ src,
                                               const int* __restrict__ dst,
                                               int* __restrict__ bcur,
                                               uint32_t* __restrict__ part) {
    __shared__ int h4[4][NBUCK];
    __shared__ int c4[4][NBUCK];
    const int t = threadIdx.x;
    const int w = (t >> 6) & 3;
    const int base = blockIdx.x * PART_CHUNK;
    const int lim = min(base + PART_CHUNK, N_EDGES);
    for (int i = t; i < 4 * NBUCK; i += 1024) ((int*)h4)[i] = 0;
    __syncthreads();
    for (int e = base + t; e < lim; e += 1024)
        atomicAdd(&h4[w][dst[e] >> BUCK_BITS], 1);
    __syncthreads();
    if (t < NBUCK) {
        int c0 = h4[0][t], c1 = h4[1][t], c2 = h4[2][t], c3 = h4[3][t];
        int tot = c0 + c1 + c2 + c3;
        int g = tot ? atomicAdd(&bcur[t], tot) : 0;
        c4[0][t] = g;
        c4[1][t] = g + c0;
        c4[2][t] = g + c0 + c1;
        c4[3][t] = g + c0 + c1 + c2;
    }
    __syncthreads();
    for (int e = base + t; e < lim; e += 1024) {
        int d = dst[e];
        int b = d >> BUCK_BITS;
        int pos = atomicAdd(&c4[w][b], 1);
        part[pos] = ((uint32_t)(d & (BUCK_SZ - 1)) << 17) | (uint32_t)src[e];
    }
}

// ---------------------------------------------------------------------------
// 2. Per-bucket counting sort -> csr (bucket-contiguous), rowbeg, deg, dinv
// ---------------------------------------------------------------------------
__global__ __launch_bounds__(256) void k_sort(const uint32_t* __restrict__ part,
                                              const int* __restrict__ bcur,
                                              int* __restrict__ csr_src,
                                              int* __restrict__ rowbeg,
                                              int* __restrict__ deg,
                                              float* __restrict__ dinv) {
    __shared__ int cnt4[4][BUCK_SZ];
    __shared__ int pref[BUCK_SZ];
    __shared__ int cur4[4][BUCK_SZ];
    const int b = blockIdx.x;
    const int t = threadIdx.x;
    const int w = t >> 6;
    const int nbase = b * BUCK_SZ;
    const int bb = b * PADB;
    const int be = bcur[b];            // final fill level
    for (int i = t; i < 4 * BUCK_SZ; i += 256) ((int*)cnt4)[i] = 0;
    __syncthreads();
    for (int j = bb + t; j < be; j += 256)
        atomicAdd(&cnt4[w][(part[j] >> 17) & (BUCK_SZ - 1)], 1);
    __syncthreads();
    int c0 = 0, c1 = 0, c2 = 0, tot = 0;
    if (t < BUCK_SZ) {
        c0 = cnt4[0][t]; c1 = cnt4[1][t]; c2 = cnt4[2][t];
        tot = c0 + c1 + c2 + cnt4[3][t];
        pref[t] = tot;
    }
    __syncthreads();
#pragma unroll
    for (int off = 1; off < BUCK_SZ; off <<= 1) {
        int v = (t >= off && t < BUCK_SZ) ? pref[t - off] : 0;
        __syncthreads();
        if (t < BUCK_SZ) pref[t] += v;
        __syncthreads();
    }
    if (t < BUCK_SZ) {
        int ex = pref[t] - tot;
        cur4[0][t] = ex;
        cur4[1][t] = ex + c0;
        cur4[2][t] = ex + c0 + c1;
        cur4[3][t] = ex + c0 + c1 + c2;
        int node = nbase + t;
        if (node < N_NODES) {
            rowbeg[node] = bb + ex;
            deg[node] = tot;
            dinv[node] = rsqrtf((float)(tot + 1));
        }
    }
    __syncthreads();
    for (int j = bb + t; j < be; j += 256) {
        uint32_t v = part[j];
        int dl = (v >> 17) & (BUCK_SZ - 1);
        int pos = bb + atomicAdd(&cur4[w][dl], 1);
        csr_src[pos] = (int)(v & 0x1FFFF);
    }
}

// ---------------------------------------------------------------------------
// 3. h0b = bf16((x @ W1) * dinv[row]); 32 rows/block, 4 outputs/thread
// ---------------------------------------------------------------------------
__global__ __launch_bounds__(256) void k_gemm1(const float* __restrict__ x,
                                               const float* __restrict__ W1,
                                               const float* __restrict__ dinv,
                                               uint16_t* __restrict__ h0b) {
    __shared__ __align__(16) float w1s[NFEAT * HIDDEN];
    __shared__ __align__(16) float xs[32 * NFEAT];
    const int tid = threadIdx.x;
    for (int i = tid; i < NFEAT * HIDDEN / 4; i += 256)
        ((fx4*)w1s)[i] = ((const fx4*)W1)[i];
    const int row0 = blockIdx.x * 32;
    const fx4* xb = (const fx4*)(x + (size_t)row0 * NFEAT);
    for (int i = tid; i < 800; i += 256)
        ((fx4*)xs)[i] = __builtin_nontemporal_load(&xb[i]);
    __syncthreads();
    const int c = tid & 31, r0 = tid >> 5;
    float a0 = 0.f, a1 = 0.f, a2 = 0.f, a3 = 0.f;
#pragma unroll 4
    for (int k = 0; k < NFEAT; ++k) {
        float wv = w1s[k * HIDDEN + c];
        a0 = fmaf(xs[(r0)      * NFEAT + k], wv, a0);
        a1 = fmaf(xs[(r0 + 8)  * NFEAT + k], wv, a1);
        a2 = fmaf(xs[(r0 + 16) * NFEAT + k], wv, a2);
        a3 = fmaf(xs[(r0 + 24) * NFEAT + k], wv, a3);
    }
    const int r = row0 + r0;
    h0b[(size_t)(r)      * HIDDEN + c] = f2bf(a0 * dinv[r]);
    h0b[(size_t)(r + 8)  * HIDDEN + c] = f2bf(a1 * dinv[r + 8]);
    h0b[(size_t)(r + 16) * HIDDEN + c] = f2bf(a2 * dinv[r + 16]);
    h0b[(size_t)(r + 24) * HIDDEN + c] = f2bf(a3 * dinv[r + 24]);
}

// ---------------------------------------------------------------------------
// 4. Layer 1: 8 lanes/node, uint2 (4xbf16) gathers => 8 edges per wave
//    instruction; software-pipelined index prefetch.
// ---------------------------------------------------------------------------
__global__ __launch_bounds__(256) void k_l1(const int* __restrict__ rowbeg,
                                            const int* __restrict__ deg,
                                            const int* __restrict__ csr_src,
                                            const float* __restrict__ dinv,
                                            const uint2* __restrict__ h0u,
                                            const float* __restrict__ b1,
                                            const float* __restrict__ W2,
                                            float* __restrict__ h2s) {
    const int t = blockIdx.x * 256 + threadIdx.x;
    const int n = t >> 3;        // 32 nodes per block (grid exact)
    const int l = t & 7;         // lane in 8-group; columns 4l..4l+3
    uint2 self = h0u[(size_t)n * 8 + l];
    float aL0 = bflo(self.x), aH0 = bfhi(self.x);
    float aL1 = bflo(self.y), aH1 = bfhi(self.y);
    const int beg = rowbeg[n];
    const int d = deg[n];
    const int end = beg + d;
    const int mainEnd = beg + (d & ~3);
    int j = beg;
    int s0, s1, s2, s3;
    if (j < mainEnd) {
        s0 = csr_src[j]; s1 = csr_src[j + 1];
        s2 = csr_src[j + 2]; s3 = csr_src[j + 3];
    }
    for (; j < mainEnd; j += 4) {
        uint2 u0 = h0u[(size_t)s0 * 8 + l];
        uint2 u1 = h0u[(size_t)s1 * 8 + l];
        uint2 u2 = h0u[(size_t)s2 * 8 + l];
        uint2 u3 = h0u[(size_t)s3 * 8 + l];
        int pj = (j + 8 <= mainEnd) ? j + 4 : beg;
        s0 = csr_src[pj];     s1 = csr_src[pj + 1];
        s2 = csr_src[pj + 2]; s3 = csr_src[pj + 3];
        aL0 += bflo(u0.x); aH0 += bfhi(u0.x); aL1 += bflo(u0.y); aH1 += bfhi(u0.y);
        aL0 += bflo(u1.x); aH0 += bfhi(u1.x); aL1 += bflo(u1.y); aH1 += bfhi(u1.y);
        aL0 += bflo(u2.x); aH0 += bfhi(u2.x); aL1 += bflo(u2.y); aH1 += bfhi(u2.y);
        aL0 += bflo(u3.x); aH0 += bfhi(u3.x); aL1 += bflo(u3.y); aH1 += bfhi(u3.y);
    }
    for (; j < end; ++j) {
        uint2 u = h0u[(size_t)csr_src[j] * 8 + l];
        aL0 += bflo(u.x); aH0 += bfhi(u.x); aL1 += bflo(u.y); aH1 += bfhi(u.y);
    }
    const int c0 = 4 * l, c1 = c0 + 1, c2 = c0 + 2, c3 = c0 + 3;
    const float din = dinv[n];
    float v0 = fmaxf(fmaf(aL0, din, b1[c0]), 0.0f);
    float v1 = fmaxf(fmaf(aH0, din, b1[c1]), 0.0f);
    float v2 = fmaxf(fmaf(aL1, din, b1[c2]), 0.0f);
    float v3 = fmaxf(fmaf(aH1, din, b1[c3]), 0.0f);
    const uint32_t fb = (uint32_t)(n * HIDDEN);
    v0 = dropout_keep(fb + c0) ? v0 * 1.25f : 0.0f;
    v1 = dropout_keep(fb + c1) ? v1 * 1.25f : 0.0f;
    v2 = dropout_keep(fb + c2) ? v2 * 1.25f : 0.0f;
    v3 = dropout_keep(fb + c3) ? v3 * 1.25f : 0.0f;
    float p0 = v0 * W2[c0 * 2] + v1 * W2[c1 * 2] + v2 * W2[c2 * 2] + v3 * W2[c3 * 2];
    float p1 = v0 * W2[c0 * 2 + 1] + v1 * W2[c1 * 2 + 1] + v2 * W2[c2 * 2 + 1] + v3 * W2[c3 * 2 + 1];
#pragma unroll
    for (int m = 4; m >= 1; m >>= 1) {
        p0 += __shfl_xor(p0, m);
        p1 += __shfl_xor(p1, m);
    }
    if (l == 0) {
        float2* o = (float2*)(h2s + (size_t)n * 2);
        *o = make_float2(p0 * din, p1 * din);
    }
}

// ---------------------------------------------------------------------------
// 5. Layer 2: register-pull, 8 lanes/node, 2x unrolled float2 gathers,
//    + b2 + log_softmax.
// ---------------------------------------------------------------------------
__global__ __launch_bounds__(256) void k_l2(const int* __restrict__ rowbeg,
                                            const int* __restrict__ deg,
                                            const int* __restrict__ csr_src,
                                            const float* __restrict__ dinv,
                                            const float* __restrict__ h2s,
                                            const float* __restrict__ b2,
                                            float* __restrict__ out) {
    int t = blockIdx.x * 256 + threadIdx.x;
    int n = t >> 3;
    int l = t & 7;
    if (n >= N_NODES) return;
    float acc0 = 0.0f, acc1 = 0.0f;
    float bcc0 = 0.0f, bcc1 = 0.0f;
    if (l == 0) {
        float2 hn = ((const float2*)h2s)[n];
        acc0 = hn.x; acc1 = hn.y;
    }
    const int beg = rowbeg[n];
    const int end = beg + deg[n];
    int j = beg + l;
    for (; j + 8 < end; j += 16) {
        int s0 = __builtin_nontemporal_load(&csr_src[j]);
        int s1 = __builtin_nontemporal_load(&csr_src[j + 8]);
        float2 h0v = ((const float2*)h2s)[s0];
        float2 h1v = ((const float2*)h2s)[s1];
        acc0 += h0v.x; acc1 += h0v.y;
        bcc0 += h1v.x; bcc1 += h1v.y;
    }
    if (j < end) {
        float2 hv = ((const float2*)h2s)[__builtin_nontemporal_load(&csr_src[j])];
        acc0 += hv.x; acc1 += hv.y;
    }
    acc0 += bcc0; acc1 += bcc1;
#pragma unroll
    for (int m = 4; m >= 1; m >>= 1) {
        acc0 += __shfl_xor(acc0, m);
        acc1 += __shfl_xor(acc1, m);
    }
    if (l == 0) {
        float din = dinv[n];
        float l0 = fmaf(acc0, din, b2[0]);
        float l1 = fmaf(acc1, din, b2[1]);
        float m = fmaxf(l0, l1);
        float lse = m + logf(expf(l0 - m) + expf(l1 - m));
        float2* o = (float2*)(out + (size_t)n * 2);
        *o = make_float2(l0 - lse, l1 - lse);
    }
}

// ---------------------------------------------------------------------------
// Launch
// ---------------------------------------------------------------------------
static inline size_t align_up(size_t x) { return (x + 255) & ~(size_t)255; }

extern "C" void kernel_launch(void* const* d_in, const int* in_sizes, int n_in,
                              void* d_out, int out_size, void* d_ws, size_t ws_size,
                              hipStream_t stream) {
    (void)n_in; (void)in_sizes; (void)out_size; (void)ws_size;

    const float* x  = (const float*)d_in[0];
    const int*   ei = (const int*)d_in[1];
    const float* W1 = (const float*)d_in[2];
    const float* b1 = (const float*)d_in[3];
    const float* W2 = (const float*)d_in[4];
    const float* b2 = (const float*)d_in[5];
    float* out = (float*)d_out;

    const int* src = ei;
    const int* dst = ei + N_EDGES;

    char* w = (char*)d_ws;
    size_t off = 0;
    int*      bcur   = (int*)(w + off);      off += align_up((size_t)NBUCK * 4);
    int*      rowbeg = (int*)(w + off);      off += align_up((size_t)N_NODES * 4);
    int*      deg    = (int*)(w + off);      off += align_up((size_t)N_NODES * 4);
    float*    dinv   = (float*)(w + off);    off += align_up((size_t)N_NODES * 4);
    uint32_t* part   = (uint32_t*)(w + off); off += align_up((size_t)NBUCK * PADB * 4);
    int*      csr    = (int*)(w + off);      off += align_up((size_t)NBUCK * PADB * 4);
    uint16_t* h0b    = (uint16_t*)(w + off); off += align_up((size_t)N_NODES * HIDDEN * 2);
    float*    h2s    = (float*)(w + off);    off += align_up((size_t)N_NODES * OUTC * 4);

    const int B = 256;
    k_init <<<(NBUCK + B - 1) / B, B, 0, stream>>>(bcur);
    k_part <<<PART_NB, 1024, 0, stream>>>(src, dst, bcur, part);
    k_sort <<<NBUCK, B, 0, stream>>>(part, bcur, csr, rowbeg, deg, dinv);
    k_gemm1<<<N_NODES / 32, B, 0, stream>>>(x, W1, dinv, h0b);
    k_l1   <<<N_NODES / 32, B, 0, stream>>>(rowbeg, deg, csr, dinv, (const uint2*)h0b, b1, W2, h2s);
    k_l2   <<<(N_NODES * 8 + B - 1) / B, B, 0, stream>>>(rowbeg, deg, csr, dinv, h2s, b2, out);
}